// Round 5
// baseline (71.312 us; speedup 1.0000x reference)
//
#include <hip/hip_runtime.h>

typedef float f32x4 __attribute__((ext_vector_type(4)));

__device__ __forceinline__ float relu_(float v) { return fmaxf(v, 0.f); }
// Intra-wave LDS fence: wave is lockstep; drain our own LDS ops + stop compiler
// reordering across the fence.
__device__ __forceinline__ void wave_sync() {
    asm volatile("s_waitcnt lgkmcnt(0)" ::: "memory");
}

// PAIRS_A = {0,0,4,1,2,2,6,3} ; PAIRS_B = {4,1,5,5,6,3,7,7} packed as nibbles
#define PA_PACK 0x36221400u
#define PB_PACK 0x77365514u

// ---------------- pre-kernel: batch-independent yk[64][20] and c0 ----------
__global__ void yk_kernel(
    const float* __restrict__ mask,
    const float* __restrict__ wm1, const float* __restrict__ bm1,
    const float* __restrict__ wm2, const float* __restrict__ bm2,
    const float* __restrict__ wm3, const float* __restrict__ bm3,
    const float* __restrict__ wk1, const float* __restrict__ bk1,
    const float* __restrict__ wk2, const float* __restrict__ bk2,
    float* __restrict__ ws)   // ws[0..1279] = yk[ij][c]; ws[1280] = c0
{
    int tid = threadIdx.x;
    int ij = tid >> 2, coff = (tid & 3) * 5;
    int i = ij >> 3, j = ij & 7;
    float m = mask[i * 8 + j];
    float a[4];
#pragma unroll
    for (int q = 0; q < 4; q++) a[q] = relu_(fmaf(m, wm1[q], bm1[q]));
    float b2[20];
#pragma unroll
    for (int c = 0; c < 20; c++) {
        float acc = bm2[c];
#pragma unroll
        for (int q = 0; q < 4; q++) acc = fmaf(a[q], wm2[q * 20 + c], acc);
        b2[c] = relu_(acc);
    }
#pragma unroll
    for (int cc = 0; cc < 5; cc++) {
        int c = coff + cc;
        float acc = bm3[c];
#pragma unroll
        for (int k = 0; k < 20; k++) acc = fmaf(b2[k], wm3[k * 20 + c], acc);
        float y = relu_(acc);
        float wkk = 0.f;
#pragma unroll
        for (int q = 0; q < 8; q++) wkk = fmaf(wk1[c * 8 + q], wk2[q], wkk);
        ws[ij * 20 + c] = y * wkk;
    }
    if (tid == 0) {
        float c0 = bk2[0];
#pragma unroll
        for (int q = 0; q < 8; q++) c0 = fmaf(bk1[q], wk2[q], c0);
        ws[1280] = c0;
    }
}

// ---------------- main kernel: 8 batches per wave, 1 batch per 8-lane group.
// Lane (g,l): computes cat[pa(l)],cat[pb(l)] inline -> pd row l (regs) ->
// u[l] (regs, +bc1) and v[l] (LDS). Stage 4: lane l = output row i=l,
// loops j over v[j] from LDS. All weights are wave-uniform -> s_load.
// Only LDS traffic: v (5 writes + 40 reads per wave per 8 batches).
__global__ __launch_bounds__(256, 4) void frap_kernel(
    const float* __restrict__ x,
    const float* __restrict__ wv1, const float* __restrict__ bv1,
    const float* __restrict__ wv2, const float* __restrict__ bv2,
    const float* __restrict__ wp1, const float* __restrict__ bp1,
    const float* __restrict__ wp2, const float* __restrict__ bp2,
    const float* __restrict__ we,  const float* __restrict__ be,
    const float* __restrict__ wc1, const float* __restrict__ bc1,
    const float* __restrict__ wc2, const float* __restrict__ bc2,
    const float* __restrict__ ykg,
    float* __restrict__ out, int Btot)
{
    // v layout (dwords): v_off(w,g,j) = w*1312 + g*164 + j*20
    // g-stride 164 -> bank offsets {0,4,8,...,28}: conflict-free group reads.
    __shared__ float s_v[4 * 1312];

    const int tid  = threadIdx.x;
    const int w    = tid >> 6;
    const int lane = tid & 63;
    const int g    = lane >> 3, l = lane & 7;
    const int b    = blockIdx.x * 32 + w * 8 + g;
    const int bb   = (b < Btot) ? b : (Btot - 1);   // clamp loads; guard stores

    const int pa = (PA_PACK >> (4 * l)) & 15;
    const int pb = (PB_PACK >> (4 * l)) & 15;

    // ---- cat rows pa and pb, computed inline (weights uniform -> s_load) ----
    float ca[8], cb[8];
    {
        const float xva = x[bb * 16 + pa];
        const float xpa = x[bb * 16 + 8 + pa];
        const float xvb = x[bb * 16 + pb];
        const float xpb = x[bb * 16 + 8 + pb];

        float t0 = relu_(fmaf(xva, wv1[0], bv1[0]));
        float t1 = relu_(fmaf(xva, wv1[1], bv1[1]));
#pragma unroll
        for (int q = 0; q < 4; q++)
            ca[q] = relu_(fmaf(t0, wv2[q], fmaf(t1, wv2[4 + q], bv2[q])));
        float p0 = relu_(fmaf(xpa, wp1[0], bp1[0]));
        float p1 = relu_(fmaf(xpa, wp1[1], bp1[1]));
#pragma unroll
        for (int q = 0; q < 4; q++)
            ca[4 + q] = relu_(fmaf(p0, wp2[q], fmaf(p1, wp2[4 + q], bp2[q])));

        float s0 = relu_(fmaf(xvb, wv1[0], bv1[0]));
        float s1 = relu_(fmaf(xvb, wv1[1], bv1[1]));
#pragma unroll
        for (int q = 0; q < 4; q++)
            cb[q] = relu_(fmaf(s0, wv2[q], fmaf(s1, wv2[4 + q], bv2[q])));
        float r0 = relu_(fmaf(xpb, wp1[0], bp1[0]));
        float r1 = relu_(fmaf(xpb, wp1[1], bp1[1]));
#pragma unroll
        for (int q = 0; q < 4; q++)
            cb[4 + q] = relu_(fmaf(r0, wp2[q], fmaf(r1, wp2[4 + q], bp2[q])));
    }

    // ---- pd row l (registers) ----
    float pd[16];
#pragma unroll
    for (int k = 0; k < 16; k++) {
        float da = be[k], db = be[k];
#pragma unroll
        for (int f = 0; f < 8; f++) {
            const float wf = we[f * 16 + k];     // uniform -> s_load
            da = fmaf(ca[f], wf, da);
            db = fmaf(cb[f], wf, db);
        }
        pd[k] = relu_(da) + relu_(db);
    }

    // ---- u[l] (regs, with bc1) and v[l] (to LDS), uniform weights ----
    float u[20];
#pragma unroll
    for (int c = 0; c < 20; c++) {
        float acc = bc1[c];                       // uniform -> s_load
#pragma unroll
        for (int k = 0; k < 16; k++)
            acc = fmaf(pd[k], wc1[k * 20 + c], acc);
        u[c] = acc;
    }
    const int vbase = w * 1312 + g * 164 + l * 20;
    {
        float vv[20];
#pragma unroll
        for (int c = 0; c < 20; c++) {
            float acc = pd[0] * wc1[16 * 20 + c];
#pragma unroll
            for (int k = 1; k < 16; k++)
                acc = fmaf(pd[k], wc1[(16 + k) * 20 + c], acc);
            vv[c] = acc;
        }
#pragma unroll
        for (int t = 0; t < 5; t++)
            *(f32x4*)&s_v[vbase + 4 * t] = *(const f32x4*)&vv[4 * t];
    }
    wave_sync();   // v visible within the wave (per-wave region, lockstep)

    // ---- stage 4: lane owns output row i=l; iterate j ----
    float z[8];
    const float c0 = ykg[1280];                   // uniform -> s_load
    const int vg = w * 1312 + g * 164;
    const float* __restrict__ ykrow = ykg + l * 160;   // (l*8+j)*20

#pragma unroll 2
    for (int j = 0; j < 8; j++) {
        float vj[20];
#pragma unroll
        for (int t = 0; t < 5; t++)
            *(f32x4*)&vj[4 * t] = *(const f32x4*)&s_v[vg + j * 20 + 4 * t];

        float s2[20];
        {
            const float h0 = relu_(u[0] + vj[0]);
#pragma unroll
            for (int c = 0; c < 20; c++)
                s2[c] = fmaf(h0, wc2[c], bc2[c]);        // s_load weights
        }
#pragma unroll
        for (int k = 1; k < 20; k++) {
            const float hk = relu_(u[k] + vj[k]);
#pragma unroll
            for (int c = 0; c < 20; c++)
                s2[c] = fmaf(hk, wc2[k * 20 + c], s2[c]); // s_load weights
        }

        float yv[20];
#pragma unroll
        for (int t = 0; t < 5; t++)
            *(f32x4*)&yv[4 * t] = *(const f32x4*)&ykrow[j * 20 + 4 * t];

        float acc = c0;
#pragma unroll
        for (int c = 0; c < 20; c++)
            acc = fmaf(relu_(s2[c]), yv[c], acc);
        z[j] = acc;
    }

    if (b < Btot) {
#pragma unroll
        for (int t = 0; t < 2; t++)
            *(f32x4*)&out[b * 64 + l * 8 + 4 * t] = *(const f32x4*)&z[4 * t];
    }
}

extern "C" void kernel_launch(void* const* d_in, const int* in_sizes, int n_in,
                              void* d_out, int out_size, void* d_ws, size_t ws_size,
                              hipStream_t stream) {
    const float* x    = (const float*)d_in[0];
    const float* mask = (const float*)d_in[1];
    const float* wv1  = (const float*)d_in[2];
    const float* bv1  = (const float*)d_in[3];
    const float* wv2  = (const float*)d_in[4];
    const float* bv2  = (const float*)d_in[5];
    const float* wp1  = (const float*)d_in[6];
    const float* bp1  = (const float*)d_in[7];
    const float* wp2  = (const float*)d_in[8];
    const float* bp2  = (const float*)d_in[9];
    const float* we   = (const float*)d_in[10];
    const float* be   = (const float*)d_in[11];
    const float* wc1  = (const float*)d_in[12];
    const float* bc1  = (const float*)d_in[13];
    const float* wc2  = (const float*)d_in[14];
    const float* bc2  = (const float*)d_in[15];
    const float* wm1  = (const float*)d_in[16];
    const float* bm1  = (const float*)d_in[17];
    const float* wm2  = (const float*)d_in[18];
    const float* bm2  = (const float*)d_in[19];
    const float* wm3  = (const float*)d_in[20];
    const float* bm3  = (const float*)d_in[21];
    const float* wk1  = (const float*)d_in[22];
    const float* bk1  = (const float*)d_in[23];
    const float* wk2  = (const float*)d_in[24];
    const float* bk2  = (const float*)d_in[25];
    float* out = (float*)d_out;
    float* ws  = (float*)d_ws;

    int Btot = in_sizes[0] / 16;                 // 32768

    yk_kernel<<<1, 256, 0, stream>>>(mask, wm1, bm1, wm2, bm2, wm3, bm3,
                                     wk1, bk1, wk2, bk2, ws);

    int grid = (Btot + 31) / 32;                 // 32 batches per 256-thr block
    frap_kernel<<<grid, 256, 0, stream>>>(
        x, wv1, bv1, wv2, bv2, wp1, bp1, wp2, bp2, we, be,
        wc1, bc1, wc2, bc2, ws, out, Btot);
}

// Round 6
// 56.353 us; speedup vs baseline: 1.2654x; 1.2654x over previous
//
#include <hip/hip_runtime.h>

typedef float f32x2 __attribute__((ext_vector_type(2)));
typedef float f32x4 __attribute__((ext_vector_type(4)));

__device__ __forceinline__ float relu_(float v) { return fmaxf(v, 0.f); }
__device__ __forceinline__ f32x2 pkrelu_(f32x2 v) {
    f32x2 r; r.x = fmaxf(v.x, 0.f); r.y = fmaxf(v.y, 0.f); return r;  // v_pk_max_f32
}
__device__ __forceinline__ f32x2 splat_(float v) { f32x2 r; r.x = v; r.y = v; return r; }
// Intra-wave LDS fence: wave is lockstep; drain our own LDS ops + stop compiler
// reordering across the fence.
__device__ __forceinline__ void wave_sync() {
    asm volatile("s_waitcnt lgkmcnt(0)" ::: "memory");
}

// PAIRS_A = {0,0,4,1,2,2,6,3} ; PAIRS_B = {4,1,5,5,6,3,7,7} packed as nibbles
#define PA_PACK 0x36221400u
#define PB_PACK 0x77365514u

// ---------------- pre-kernel: batch-independent yk[64][20] and c0 ----------
__global__ void yk_kernel(
    const float* __restrict__ mask,
    const float* __restrict__ wm1, const float* __restrict__ bm1,
    const float* __restrict__ wm2, const float* __restrict__ bm2,
    const float* __restrict__ wm3, const float* __restrict__ bm3,
    const float* __restrict__ wk1, const float* __restrict__ bk1,
    const float* __restrict__ wk2, const float* __restrict__ bk2,
    float* __restrict__ ws)   // ws[0..1279] = yk[ij][c]; ws[1280] = c0
{
    int tid = threadIdx.x;
    int ij = tid >> 2, coff = (tid & 3) * 5;
    int i = ij >> 3, j = ij & 7;
    float m = mask[i * 8 + j];
    float a[4];
#pragma unroll
    for (int q = 0; q < 4; q++) a[q] = relu_(fmaf(m, wm1[q], bm1[q]));
    float b2[20];
#pragma unroll
    for (int c = 0; c < 20; c++) {
        float acc = bm2[c];
#pragma unroll
        for (int q = 0; q < 4; q++) acc = fmaf(a[q], wm2[q * 20 + c], acc);
        b2[c] = relu_(acc);
    }
#pragma unroll
    for (int cc = 0; cc < 5; cc++) {
        int c = coff + cc;
        float acc = bm3[c];
#pragma unroll
        for (int k = 0; k < 20; k++) acc = fmaf(b2[k], wm3[k * 20 + c], acc);
        float y = relu_(acc);
        float wkk = 0.f;
#pragma unroll
        for (int q = 0; q < 8; q++) wkk = fmaf(wk1[c * 8 + q], wk2[q], wkk);
        ws[ij * 20 + c] = y * wkk;
    }
    if (tid == 0) {
        float c0 = bk2[0];
#pragma unroll
        for (int q = 0; q < 8; q++) c0 = fmaf(bk1[q], wk2[q], c0);
        ws[1280] = c0;
    }
}

// ---------------- main kernel: 8 batches per wave, 1 batch per 8-lane group.
// Lane (g,l): cat[pa(l)],cat[pb(l)] inline -> pd row l (regs, pk) ->
// u[l] (regs, +bc1, pk) and v[l] (LDS). Stage 4: lane l = output row i=l,
// j-loop (unroll 1) reads v[j] from LDS. All weights wave-uniform -> s_load.
// z_j round-trips through LDS scratch to avoid runtime-indexed local array.
__global__ __launch_bounds__(256) void frap_kernel(
    const float* __restrict__ x,
    const float* __restrict__ wv1, const float* __restrict__ bv1,
    const float* __restrict__ wv2, const float* __restrict__ bv2,
    const float* __restrict__ wp1, const float* __restrict__ bp1,
    const float* __restrict__ wp2, const float* __restrict__ bp2,
    const float* __restrict__ we,  const float* __restrict__ be,
    const float* __restrict__ wc1, const float* __restrict__ bc1,
    const float* __restrict__ wc2, const float* __restrict__ bc2,
    const float* __restrict__ ykg,
    float* __restrict__ out, int Btot)
{
    // v layout (dwords): v_off(w,g,j) = w*1312 + g*164 + j*20
    // g-stride 164 -> 8 groups span all 32 banks for b128 reads: conflict-free.
    __shared__ float s_v[4 * 1312];
    // z scratch: zoff(w,g,l,j) = w*520 + g*65 + l*8 + j  (2-way banking = free)
    __shared__ float s_z[4 * 520];

    const int tid  = threadIdx.x;
    const int w    = tid >> 6;
    const int lane = tid & 63;
    const int g    = lane >> 3, l = lane & 7;
    const int b    = blockIdx.x * 32 + w * 8 + g;
    const int bb   = (b < Btot) ? b : (Btot - 1);   // clamp loads; guard stores

    const int pa = (PA_PACK >> (4 * l)) & 15;
    const int pb = (PB_PACK >> (4 * l)) & 15;

    // ---- cat rows pa and pb, computed inline (weights uniform -> s_load) ----
    float ca[8], cb[8];
    {
        const float xva = x[bb * 16 + pa];
        const float xpa = x[bb * 16 + 8 + pa];
        const float xvb = x[bb * 16 + pb];
        const float xpb = x[bb * 16 + 8 + pb];

        float t0 = relu_(fmaf(xva, wv1[0], bv1[0]));
        float t1 = relu_(fmaf(xva, wv1[1], bv1[1]));
#pragma unroll
        for (int q = 0; q < 4; q++)
            ca[q] = relu_(fmaf(t0, wv2[q], fmaf(t1, wv2[4 + q], bv2[q])));
        float p0 = relu_(fmaf(xpa, wp1[0], bp1[0]));
        float p1 = relu_(fmaf(xpa, wp1[1], bp1[1]));
#pragma unroll
        for (int q = 0; q < 4; q++)
            ca[4 + q] = relu_(fmaf(p0, wp2[q], fmaf(p1, wp2[4 + q], bp2[q])));

        float s0 = relu_(fmaf(xvb, wv1[0], bv1[0]));
        float s1 = relu_(fmaf(xvb, wv1[1], bv1[1]));
#pragma unroll
        for (int q = 0; q < 4; q++)
            cb[q] = relu_(fmaf(s0, wv2[q], fmaf(s1, wv2[4 + q], bv2[q])));
        float r0 = relu_(fmaf(xpb, wp1[0], bp1[0]));
        float r1 = relu_(fmaf(xpb, wp1[1], bp1[1]));
#pragma unroll
        for (int q = 0; q < 4; q++)
            cb[4 + q] = relu_(fmaf(r0, wp2[q], fmaf(r1, wp2[4 + q], bp2[q])));
    }

    // ---- pd row l: pk over k-pairs, f-order sequential (matches reference) ----
    f32x2 pd2[8];
#pragma unroll
    for (int kk = 0; kk < 8; kk++) {
        const int k = 2 * kk;
        f32x2 da2, db2;
        da2.x = be[k]; da2.y = be[k + 1];            // s_load pair
        db2 = da2;
#pragma unroll
        for (int f = 0; f < 8; f++) {
            f32x2 wf2;
            wf2.x = we[f * 16 + k];                  // contiguous -> s_load x2
            wf2.y = we[f * 16 + k + 1];
            da2 += splat_(ca[f]) * wf2;              // v_pk_fma_f32
            db2 += splat_(cb[f]) * wf2;
        }
        pd2[kk] = pkrelu_(da2) + pkrelu_(db2);
    }

    // ---- u[l] (regs, +bc1) and v[l] (LDS), pk over c-pairs ----
    f32x2 u2[10];
#pragma unroll
    for (int c = 0; c < 10; c++) { u2[c].x = bc1[2 * c]; u2[c].y = bc1[2 * c + 1]; }
#pragma unroll
    for (int k = 0; k < 16; k++) {
        const float pk_s = (k & 1) ? pd2[k >> 1].y : pd2[k >> 1].x;
        const f32x2 pv = splat_(pk_s);
#pragma unroll
        for (int c = 0; c < 10; c++) {
            f32x2 w2;
            w2.x = wc1[k * 20 + 2 * c];              // s_load
            w2.y = wc1[k * 20 + 2 * c + 1];
            u2[c] += pv * w2;
        }
    }
    const int vbase = w * 1312 + g * 164 + l * 20;
    {
        f32x2 vv[10];
#pragma unroll
        for (int c = 0; c < 10; c++) { vv[c].x = 0.f; vv[c].y = 0.f; }
#pragma unroll
        for (int k = 0; k < 16; k++) {
            const float pk_s = (k & 1) ? pd2[k >> 1].y : pd2[k >> 1].x;
            const f32x2 pv = splat_(pk_s);
#pragma unroll
            for (int c = 0; c < 10; c++) {
                f32x2 w2;
                w2.x = wc1[(16 + k) * 20 + 2 * c];   // s_load
                w2.y = wc1[(16 + k) * 20 + 2 * c + 1];
                vv[c] += pv * w2;
            }
        }
#pragma unroll
        for (int c = 0; c < 10; c++)
            *(f32x2*)&s_v[vbase + 2 * c] = vv[c];    // ds_write_b64
    }
    wave_sync();   // v visible within the wave (per-wave region, lockstep)

    // ---- stage 4: lane owns output row i=l; iterate j (unroll 1!) ----
    const float c0 = ykg[1280];                      // uniform -> s_load
    const int vg = w * 1312 + g * 164;
    const int zbase = w * 520 + g * 65 + l * 8;
    const float* __restrict__ ykrow = ykg + l * 160; // (l*8+j)*20

#pragma unroll 1
    for (int j = 0; j < 8; j++) {
        // v[j]: 5x ds_read_b128, broadcast within each 8-lane group
        f32x4 a0 = *(const f32x4*)&s_v[vg + j * 20 + 0];
        f32x4 a1 = *(const f32x4*)&s_v[vg + j * 20 + 4];
        f32x4 a2 = *(const f32x4*)&s_v[vg + j * 20 + 8];
        f32x4 a3 = *(const f32x4*)&s_v[vg + j * 20 + 12];
        f32x4 a4 = *(const f32x4*)&s_v[vg + j * 20 + 16];

        f32x2 h2[10];
        { f32x2 t; t.x = a0.x; t.y = a0.y; h2[0] = pkrelu_(u2[0] + t); }
        { f32x2 t; t.x = a0.z; t.y = a0.w; h2[1] = pkrelu_(u2[1] + t); }
        { f32x2 t; t.x = a1.x; t.y = a1.y; h2[2] = pkrelu_(u2[2] + t); }
        { f32x2 t; t.x = a1.z; t.y = a1.w; h2[3] = pkrelu_(u2[3] + t); }
        { f32x2 t; t.x = a2.x; t.y = a2.y; h2[4] = pkrelu_(u2[4] + t); }
        { f32x2 t; t.x = a2.z; t.y = a2.w; h2[5] = pkrelu_(u2[5] + t); }
        { f32x2 t; t.x = a3.x; t.y = a3.y; h2[6] = pkrelu_(u2[6] + t); }
        { f32x2 t; t.x = a3.z; t.y = a3.w; h2[7] = pkrelu_(u2[7] + t); }
        { f32x2 t; t.x = a4.x; t.y = a4.y; h2[8] = pkrelu_(u2[8] + t); }
        { f32x2 t; t.x = a4.z; t.y = a4.w; h2[9] = pkrelu_(u2[9] + t); }

        f32x2 s2[10];
#pragma unroll
        for (int c = 0; c < 10; c++) { s2[c].x = bc2[2 * c]; s2[c].y = bc2[2 * c + 1]; }
#pragma unroll
        for (int k = 0; k < 20; k++) {
            const float hk = (k & 1) ? h2[k >> 1].y : h2[k >> 1].x;
            const f32x2 hv = splat_(hk);
#pragma unroll
            for (int c = 0; c < 10; c++) {
                f32x2 w2;
                w2.x = wc2[k * 20 + 2 * c];          // s_load
                w2.y = wc2[k * 20 + 2 * c + 1];
                s2[c] += hv * w2;                    // v_pk_fma_f32
            }
        }

        // yk row for (i=l, j): 5x global b128 (L1/L2-hot)
        f32x4 y0 = *(const f32x4*)&ykrow[j * 20 + 0];
        f32x4 y1 = *(const f32x4*)&ykrow[j * 20 + 4];
        f32x4 y2 = *(const f32x4*)&ykrow[j * 20 + 8];
        f32x4 y3 = *(const f32x4*)&ykrow[j * 20 + 12];
        f32x4 y4 = *(const f32x4*)&ykrow[j * 20 + 16];

        f32x2 z2; z2.x = 0.f; z2.y = 0.f;
        { f32x2 t; t.x = y0.x; t.y = y0.y; z2 += pkrelu_(s2[0]) * t; }
        { f32x2 t; t.x = y0.z; t.y = y0.w; z2 += pkrelu_(s2[1]) * t; }
        { f32x2 t; t.x = y1.x; t.y = y1.y; z2 += pkrelu_(s2[2]) * t; }
        { f32x2 t; t.x = y1.z; t.y = y1.w; z2 += pkrelu_(s2[3]) * t; }
        { f32x2 t; t.x = y2.x; t.y = y2.y; z2 += pkrelu_(s2[4]) * t; }
        { f32x2 t; t.x = y2.z; t.y = y2.w; z2 += pkrelu_(s2[5]) * t; }
        { f32x2 t; t.x = y3.x; t.y = y3.y; z2 += pkrelu_(s2[6]) * t; }
        { f32x2 t; t.x = y3.z; t.y = y3.w; z2 += pkrelu_(s2[7]) * t; }
        { f32x2 t; t.x = y4.x; t.y = y4.y; z2 += pkrelu_(s2[8]) * t; }
        { f32x2 t; t.x = y4.z; t.y = y4.w; z2 += pkrelu_(s2[9]) * t; }

        s_z[zbase + j] = c0 + z2.x + z2.y;           // ds_write_b32
    }
    wave_sync();

    if (b < Btot) {
        f32x4 o0 = *(const f32x4*)&s_z[zbase + 0];
        f32x4 o1 = *(const f32x4*)&s_z[zbase + 4];
        *(f32x4*)&out[b * 64 + l * 8 + 0] = o0;
        *(f32x4*)&out[b * 64 + l * 8 + 4] = o1;
    }
}

extern "C" void kernel_launch(void* const* d_in, const int* in_sizes, int n_in,
                              void* d_out, int out_size, void* d_ws, size_t ws_size,
                              hipStream_t stream) {
    const float* x    = (const float*)d_in[0];
    const float* mask = (const float*)d_in[1];
    const float* wv1  = (const float*)d_in[2];
    const float* bv1  = (const float*)d_in[3];
    const float* wv2  = (const float*)d_in[4];
    const float* bv2  = (const float*)d_in[5];
    const float* wp1  = (const float*)d_in[6];
    const float* bp1  = (const float*)d_in[7];
    const float* wp2  = (const float*)d_in[8];
    const float* bp2  = (const float*)d_in[9];
    const float* we   = (const float*)d_in[10];
    const float* be   = (const float*)d_in[11];
    const float* wc1  = (const float*)d_in[12];
    const float* bc1  = (const float*)d_in[13];
    const float* wc2  = (const float*)d_in[14];
    const float* bc2  = (const float*)d_in[15];
    const float* wm1  = (const float*)d_in[16];
    const float* bm1  = (const float*)d_in[17];
    const float* wm2  = (const float*)d_in[18];
    const float* bm2  = (const float*)d_in[19];
    const float* wm3  = (const float*)d_in[20];
    const float* bm3  = (const float*)d_in[21];
    const float* wk1  = (const float*)d_in[22];
    const float* bk1  = (const float*)d_in[23];
    const float* wk2  = (const float*)d_in[24];
    const float* bk2  = (const float*)d_in[25];
    float* out = (float*)d_out;
    float* ws  = (float*)d_ws;

    int Btot = in_sizes[0] / 16;                 // 32768

    yk_kernel<<<1, 256, 0, stream>>>(mask, wm1, bm1, wm2, bm2, wm3, bm3,
                                     wk1, bk1, wk2, bk2, ws);

    int grid = (Btot + 31) / 32;                 // 32 batches per 256-thr block
    frap_kernel<<<grid, 256, 0, stream>>>(
        x, wv1, bv1, wv2, bv2, wp1, bp1, wp2, bp2, we, be,
        wc1, bc1, wc2, bc2, ws, out, Btot);
}

// Round 9
// 44.680 us; speedup vs baseline: 1.5961x; 1.2613x over previous
//
#include <hip/hip_runtime.h>

typedef float f32x2 __attribute__((ext_vector_type(2)));
typedef float f32x4 __attribute__((ext_vector_type(4)));

__device__ __forceinline__ float relu_(float v) { return fmaxf(v, 0.f); }
// Intra-wave LDS fence: wave is lockstep; drain our own LDS ops + stop compiler
// reordering across the fence.
__device__ __forceinline__ void wave_sync() {
    asm volatile("s_waitcnt lgkmcnt(0)" ::: "memory");
}
// acc += hv * w   (w in SGPR pair -> zero VALU cost for the weight operand)
__device__ __forceinline__ void pk_fma_sw(f32x2& acc, f32x2 hv, f32x2 w) {
    asm("v_pk_fma_f32 %0, %1, %2, %0" : "+v"(acc) : "v"(hv), "s"(w));
}
// acc += a * b   (both VGPR pairs)
__device__ __forceinline__ void pk_fma_vv(f32x2& acc, f32x2 a, f32x2 b) {
    asm("v_pk_fma_f32 %0, %1, %2, %0" : "+v"(acc) : "v"(a), "v"(b));
}
// NOTE: v_pk_max_f32 does NOT exist on gfx950 (CDNA4 packed-f32 VOP3P set is
// only pk_fma/pk_mul/pk_add/pk_mov) — relu on pairs is 2x v_max_f32.
__device__ __forceinline__ f32x2 pk_relu(f32x2 a) {
    f32x2 r; r.x = fmaxf(a.x, 0.f); r.y = fmaxf(a.y, 0.f); return r;
}

// PAIRS_A = {0,0,4,1,2,2,6,3} ; PAIRS_B = {4,1,5,5,6,3,7,7} packed as nibbles
#define PA_PACK 0x36221400u
#define PB_PACK 0x77365514u

// ---------------- pre-kernel: batch-independent yk[64][20] and c0 ----------
__global__ void yk_kernel(
    const float* __restrict__ mask,
    const float* __restrict__ wm1, const float* __restrict__ bm1,
    const float* __restrict__ wm2, const float* __restrict__ bm2,
    const float* __restrict__ wm3, const float* __restrict__ bm3,
    const float* __restrict__ wk1, const float* __restrict__ bk1,
    const float* __restrict__ wk2, const float* __restrict__ bk2,
    float* __restrict__ ws)   // ws[0..1279] = yk[ij][c]; ws[1280] = c0
{
    int tid = threadIdx.x;
    int ij = tid >> 2, coff = (tid & 3) * 5;
    int i = ij >> 3, j = ij & 7;
    float m = mask[i * 8 + j];
    float a[4];
#pragma unroll
    for (int q = 0; q < 4; q++) a[q] = relu_(fmaf(m, wm1[q], bm1[q]));
    float b2[20];
#pragma unroll
    for (int c = 0; c < 20; c++) {
        float acc = bm2[c];
#pragma unroll
        for (int q = 0; q < 4; q++) acc = fmaf(a[q], wm2[q * 20 + c], acc);
        b2[c] = relu_(acc);
    }
#pragma unroll
    for (int cc = 0; cc < 5; cc++) {
        int c = coff + cc;
        float acc = bm3[c];
#pragma unroll
        for (int k = 0; k < 20; k++) acc = fmaf(b2[k], wm3[k * 20 + c], acc);
        float y = relu_(acc);
        float wkk = 0.f;
#pragma unroll
        for (int q = 0; q < 8; q++) wkk = fmaf(wk1[c * 8 + q], wk2[q], wkk);
        ws[ij * 20 + c] = y * wkk;
    }
    if (tid == 0) {
        float c0 = bk2[0];
#pragma unroll
        for (int q = 0; q < 8; q++) c0 = fmaf(bk1[q], wk2[q], c0);
        ws[1280] = c0;
    }
}

// ---------------- main kernel: 4 batches per wave, 16 lanes per batch.
// lane = (g, jh, i): g = batch group (4/wave), i = output row (8), jh = j-half.
// Each lane: cat rows pa(i),pb(i) -> pd row i (regs) -> u[i] (regs) + v[i]
// (LDS, written by jh=0 half). Stage 4: 2 iterations of a j-pair
// (j = jh*4 + 2t + {0,1}); s2 matmul via inline-asm v_pk_fma_f32 with
// SGPR-pair weights (wave-uniform s_load), accumulators in VGPR pairs.
__global__ void frap_kernel(
    const float* __restrict__ x,
    const float* __restrict__ wv1, const float* __restrict__ bv1,
    const float* __restrict__ wv2, const float* __restrict__ bv2,
    const float* __restrict__ wp1, const float* __restrict__ bp1,
    const float* __restrict__ wp2, const float* __restrict__ bp2,
    const float* __restrict__ we,  const float* __restrict__ be,
    const float* __restrict__ wc1, const float* __restrict__ bc1,
    const float* __restrict__ wc2, const float* __restrict__ bc2,
    const float* __restrict__ ykg,
    float* __restrict__ out, int Btot)
{
    // v layout (dwords): voff(w,g,r) = w*656 + g*164 + r*20
    // row stride 20 -> 8 rows start at banks {0,20,8,28,16,4,24,12} (distinct);
    // group stride 164 -> +4 banks per group. b128 reads conflict-free.
    __shared__ float s_v[4 * 656];

    const int tid  = threadIdx.x;
    const int w    = tid >> 6;
    const int lane = tid & 63;
    const int g    = lane >> 4;
    const int jh   = (lane >> 3) & 1;
    const int i    = lane & 7;
    const int b    = blockIdx.x * 16 + w * 4 + g;
    const int bb   = (b < Btot) ? b : (Btot - 1);   // clamp loads; guard stores

    const int pa = (PA_PACK >> (4 * i)) & 15;
    const int pb = (PB_PACK >> (4 * i)) & 15;

    // ---- cat rows pa and pb, inline (weights uniform -> s_load) ----
    float ca[8], cb[8];
    {
        const float xva = x[bb * 16 + pa];
        const float xpa = x[bb * 16 + 8 + pa];
        const float xvb = x[bb * 16 + pb];
        const float xpb = x[bb * 16 + 8 + pb];

        float t0 = relu_(fmaf(xva, wv1[0], bv1[0]));
        float t1 = relu_(fmaf(xva, wv1[1], bv1[1]));
#pragma unroll
        for (int q = 0; q < 4; q++)
            ca[q] = relu_(fmaf(t0, wv2[q], fmaf(t1, wv2[4 + q], bv2[q])));
        float p0 = relu_(fmaf(xpa, wp1[0], bp1[0]));
        float p1 = relu_(fmaf(xpa, wp1[1], bp1[1]));
#pragma unroll
        for (int q = 0; q < 4; q++)
            ca[4 + q] = relu_(fmaf(p0, wp2[q], fmaf(p1, wp2[4 + q], bp2[q])));

        float s0 = relu_(fmaf(xvb, wv1[0], bv1[0]));
        float s1 = relu_(fmaf(xvb, wv1[1], bv1[1]));
#pragma unroll
        for (int q = 0; q < 4; q++)
            cb[q] = relu_(fmaf(s0, wv2[q], fmaf(s1, wv2[4 + q], bv2[q])));
        float r0 = relu_(fmaf(xpb, wp1[0], bp1[0]));
        float r1 = relu_(fmaf(xpb, wp1[1], bp1[1]));
#pragma unroll
        for (int q = 0; q < 4; q++)
            cb[4 + q] = relu_(fmaf(r0, wp2[q], fmaf(r1, wp2[4 + q], bp2[q])));
    }

    // ---- pd row i (scalar fmac, SGPR weights: v_fmac v, s, v) ----
    float pd[16];
#pragma unroll
    for (int k = 0; k < 16; k++) {
        float da = be[k], db = be[k];
#pragma unroll
        for (int f = 0; f < 8; f++) {
            const float wf = we[f * 16 + k];          // uniform -> s_load
            da = fmaf(ca[f], wf, da);
            db = fmaf(cb[f], wf, db);
        }
        pd[k] = relu_(da) + relu_(db);
    }

    // ---- u[i] (regs) and v[i] (LDS) via asm pk_fma with SGPR weights ----
    f32x2 u2[10];
    union { f32x4 q[5]; f32x2 p[10]; } vvu;
#pragma unroll
    for (int c = 0; c < 10; c++) {
        u2[c] = *(const f32x2*)&bc1[2 * c];           // s_load pair -> 2 movs
        vvu.p[c].x = 0.f; vvu.p[c].y = 0.f;
    }
#pragma unroll
    for (int k = 0; k < 16; k++) {
        f32x2 pv; pv.x = pd[k]; pv.y = pd[k];
#pragma unroll
        for (int c = 0; c < 10; c++) {
            pk_fma_sw(u2[c],    pv, *(const f32x2*)&wc1[k * 20 + 2 * c]);
            pk_fma_sw(vvu.p[c], pv, *(const f32x2*)&wc1[(16 + k) * 20 + 2 * c]);
        }
    }
    const int vbase = w * 656 + g * 164 + i * 20;
    if (jh == 0) {
#pragma unroll
        for (int p = 0; p < 5; p++)
            *(f32x4*)&s_v[vbase + 4 * p] = vvu.q[p];  // 5x ds_write_b128
    }
    wave_sync();   // per-wave LDS region; wave lockstep => visible to all lanes

    // ---- stage 4: lane owns (i, jh); 2 iterations of a j-pair ----
    const float c0 = ykg[1280];                       // uniform -> s_load
    const int vg = w * 656 + g * 164;
    const float* __restrict__ ykrow = ykg + i * 160;  // + j*20

#pragma unroll 1
    for (int t = 0; t < 2; t++) {
        const int jA = jh * 4 + 2 * t;                // and jB = jA+1

        union { f32x4 q[5]; float f[20]; } va, vb;
#pragma unroll
        for (int p = 0; p < 5; p++) {
            va.q[p] = *(const f32x4*)&s_v[vg + jA * 20 + 4 * p];
            vb.q[p] = *(const f32x4*)&s_v[vg + (jA + 1) * 20 + 4 * p];
        }

        f32x2 sA[10], sB[10];
#pragma unroll
        for (int c = 0; c < 10; c++) {
            const f32x2 b2 = *(const f32x2*)&bc2[2 * c];
            sA[c] = b2; sB[c] = b2;
        }
#pragma unroll
        for (int k = 0; k < 20; k++) {
            const float uk = (k & 1) ? u2[k >> 1].y : u2[k >> 1].x;
            const float hA = relu_(uk + va.f[k]);
            const float hB = relu_(uk + vb.f[k]);
            f32x2 hva; hva.x = hA; hva.y = hA;
            f32x2 hvb; hvb.x = hB; hvb.y = hB;
#pragma unroll
            for (int c = 0; c < 10; c++) {
                const f32x2 w2 = *(const f32x2*)&wc2[k * 20 + 2 * c];  // s_load
                pk_fma_sw(sA[c], hva, w2);
                pk_fma_sw(sB[c], hvb, w2);
            }
        }

        // epilogue: z = c0 + sum relu(s2)*yk  (yk rows L1-hot, b128 loads)
        union { f32x4 q[5]; f32x2 p[10]; } ya, yb;
#pragma unroll
        for (int p = 0; p < 5; p++) {
            ya.q[p] = *(const f32x4*)&ykrow[jA * 20 + 4 * p];
            yb.q[p] = *(const f32x4*)&ykrow[(jA + 1) * 20 + 4 * p];
        }
        f32x2 zA2; zA2.x = 0.f; zA2.y = 0.f;
        f32x2 zB2; zB2.x = 0.f; zB2.y = 0.f;
#pragma unroll
        for (int c = 0; c < 10; c++) {
            pk_fma_vv(zA2, pk_relu(sA[c]), ya.p[c]);
            pk_fma_vv(zB2, pk_relu(sB[c]), yb.p[c]);
        }
        if (b < Btot) {
            f32x2 zz;
            zz.x = c0 + zA2.x + zA2.y;
            zz.y = c0 + zB2.x + zB2.y;
            *(f32x2*)&out[b * 64 + i * 8 + jA] = zz;  // 8B-aligned (jA even)
        }
    }
}

extern "C" void kernel_launch(void* const* d_in, const int* in_sizes, int n_in,
                              void* d_out, int out_size, void* d_ws, size_t ws_size,
                              hipStream_t stream) {
    const float* x    = (const float*)d_in[0];
    const float* mask = (const float*)d_in[1];
    const float* wv1  = (const float*)d_in[2];
    const float* bv1  = (const float*)d_in[3];
    const float* wv2  = (const float*)d_in[4];
    const float* bv2  = (const float*)d_in[5];
    const float* wp1  = (const float*)d_in[6];
    const float* bp1  = (const float*)d_in[7];
    const float* wp2  = (const float*)d_in[8];
    const float* bp2  = (const float*)d_in[9];
    const float* we   = (const float*)d_in[10];
    const float* be   = (const float*)d_in[11];
    const float* wc1  = (const float*)d_in[12];
    const float* bc1  = (const float*)d_in[13];
    const float* wc2  = (const float*)d_in[14];
    const float* bc2  = (const float*)d_in[15];
    const float* wm1  = (const float*)d_in[16];
    const float* bm1  = (const float*)d_in[17];
    const float* wm2  = (const float*)d_in[18];
    const float* bm2  = (const float*)d_in[19];
    const float* wm3  = (const float*)d_in[20];
    const float* bm3  = (const float*)d_in[21];
    const float* wk1  = (const float*)d_in[22];
    const float* bk1  = (const float*)d_in[23];
    const float* wk2  = (const float*)d_in[24];
    const float* bk2  = (const float*)d_in[25];
    float* out = (float*)d_out;
    float* ws  = (float*)d_ws;

    int Btot = in_sizes[0] / 16;                 // 32768

    yk_kernel<<<1, 256, 0, stream>>>(mask, wm1, bm1, wm2, bm2, wm3, bm3,
                                     wk1, bk1, wk2, bk2, ws);

    int grid = (Btot + 15) / 16;                 // 16 batches per 256-thr block
    frap_kernel<<<grid, 256, 0, stream>>>(
        x, wv1, bv1, wv2, bv2, wp1, bp1, wp2, bp2, we, be,
        wc1, bc1, wc2, bc2, ws, out, Btot);
}

// Round 10
// 42.837 us; speedup vs baseline: 1.6647x; 1.0430x over previous
//
#include <hip/hip_runtime.h>

typedef float f32x2 __attribute__((ext_vector_type(2)));
typedef float f32x4 __attribute__((ext_vector_type(4)));

__device__ __forceinline__ float relu_(float v) { return fmaxf(v, 0.f); }
// Intra-wave LDS fence: wave is lockstep; drain our own LDS ops + stop compiler
// reordering across the fence.
__device__ __forceinline__ void wave_sync() {
    asm volatile("s_waitcnt lgkmcnt(0)" ::: "memory");
}
// acc += hv * w   (w in SGPR pair -> zero VALU cost for the weight operand)
__device__ __forceinline__ void pk_fma_sw(f32x2& acc, f32x2 hv, f32x2 w) {
    asm("v_pk_fma_f32 %0, %1, %2, %0" : "+v"(acc) : "v"(hv), "s"(w));
}
// acc += a * b   (both VGPR pairs)
__device__ __forceinline__ void pk_fma_vv(f32x2& acc, f32x2 a, f32x2 b) {
    asm("v_pk_fma_f32 %0, %1, %2, %0" : "+v"(acc) : "v"(a), "v"(b));
}
// NOTE: v_pk_max_f32 does NOT exist on gfx950 — relu on pairs is 2x v_max_f32.
__device__ __forceinline__ f32x2 pk_relu(f32x2 a) {
    f32x2 r; r.x = fmaxf(a.x, 0.f); r.y = fmaxf(a.y, 0.f); return r;
}

// PAIRS_A = {0,0,4,1,2,2,6,3} ; PAIRS_B = {4,1,5,5,6,3,7,7} packed as nibbles
#define PA_PACK 0x36221400u
#define PB_PACK 0x77365514u

// ---------------- pre-kernel: batch-independent yk[64][20] and c0 ----------
__global__ void yk_kernel(
    const float* __restrict__ mask,
    const float* __restrict__ wm1, const float* __restrict__ bm1,
    const float* __restrict__ wm2, const float* __restrict__ bm2,
    const float* __restrict__ wm3, const float* __restrict__ bm3,
    const float* __restrict__ wk1, const float* __restrict__ bk1,
    const float* __restrict__ wk2, const float* __restrict__ bk2,
    float* __restrict__ ws)   // ws[0..1279] = yk[ij][c]; ws[1280] = c0
{
    int tid = threadIdx.x;
    int ij = tid >> 2, coff = (tid & 3) * 5;
    int i = ij >> 3, j = ij & 7;
    float m = mask[i * 8 + j];
    float a[4];
#pragma unroll
    for (int q = 0; q < 4; q++) a[q] = relu_(fmaf(m, wm1[q], bm1[q]));
    float b2[20];
#pragma unroll
    for (int c = 0; c < 20; c++) {
        float acc = bm2[c];
#pragma unroll
        for (int q = 0; q < 4; q++) acc = fmaf(a[q], wm2[q * 20 + c], acc);
        b2[c] = relu_(acc);
    }
#pragma unroll
    for (int cc = 0; cc < 5; cc++) {
        int c = coff + cc;
        float acc = bm3[c];
#pragma unroll
        for (int k = 0; k < 20; k++) acc = fmaf(b2[k], wm3[k * 20 + c], acc);
        float y = relu_(acc);
        float wkk = 0.f;
#pragma unroll
        for (int q = 0; q < 8; q++) wkk = fmaf(wk1[c * 8 + q], wk2[q], wkk);
        ws[ij * 20 + c] = y * wkk;
    }
    if (tid == 0) {
        float c0 = bk2[0];
#pragma unroll
        for (int q = 0; q < 8; q++) c0 = fmaf(bk1[q], wk2[q], c0);
        ws[1280] = c0;
    }
}

// ---------------- main kernel: 4 batches per wave, 16 lanes per batch.
// lane = (g, jh, i). Each lane: cat rows pa(i),pb(i) -> pd row i (regs) ->
// u[i] (regs) + v[i] (LDS, jh=0 half writes). Stage 4: FOUR iterations,
// ONE j each (j = jh*4 + t) — keeps peak live set ~66 VGPRs so that with
// __launch_bounds__(256,5) (cap ~96) NOTHING is demoted to AGPRs.
__global__ __launch_bounds__(256, 5) void frap_kernel(
    const float* __restrict__ x,
    const float* __restrict__ wv1, const float* __restrict__ bv1,
    const float* __restrict__ wv2, const float* __restrict__ bv2,
    const float* __restrict__ wp1, const float* __restrict__ bp1,
    const float* __restrict__ wp2, const float* __restrict__ bp2,
    const float* __restrict__ we,  const float* __restrict__ be,
    const float* __restrict__ wc1, const float* __restrict__ bc1,
    const float* __restrict__ wc2, const float* __restrict__ bc2,
    const float* __restrict__ ykg,
    float* __restrict__ out, int Btot)
{
    // v layout (dwords): voff(w,g,r) = w*656 + g*164 + r*20
    // row stride 20 -> 8 rows start at distinct banks; group stride 164 ->
    // +4 banks per group. b128 reads conflict-free.
    __shared__ float s_v[4 * 656];

    const int tid  = threadIdx.x;
    const int w    = tid >> 6;
    const int lane = tid & 63;
    const int g    = lane >> 4;
    const int jh   = (lane >> 3) & 1;
    const int i    = lane & 7;
    const int b    = blockIdx.x * 16 + w * 4 + g;
    const int bb   = (b < Btot) ? b : (Btot - 1);   // clamp loads; guard stores

    const int pa = (PA_PACK >> (4 * i)) & 15;
    const int pb = (PB_PACK >> (4 * i)) & 15;

    // ---- cat rows pa and pb, inline (weights uniform -> s_load) ----
    float ca[8], cb[8];
    {
        const float xva = x[bb * 16 + pa];
        const float xpa = x[bb * 16 + 8 + pa];
        const float xvb = x[bb * 16 + pb];
        const float xpb = x[bb * 16 + 8 + pb];

        float t0 = relu_(fmaf(xva, wv1[0], bv1[0]));
        float t1 = relu_(fmaf(xva, wv1[1], bv1[1]));
#pragma unroll
        for (int q = 0; q < 4; q++)
            ca[q] = relu_(fmaf(t0, wv2[q], fmaf(t1, wv2[4 + q], bv2[q])));
        float p0 = relu_(fmaf(xpa, wp1[0], bp1[0]));
        float p1 = relu_(fmaf(xpa, wp1[1], bp1[1]));
#pragma unroll
        for (int q = 0; q < 4; q++)
            ca[4 + q] = relu_(fmaf(p0, wp2[q], fmaf(p1, wp2[4 + q], bp2[q])));

        float s0 = relu_(fmaf(xvb, wv1[0], bv1[0]));
        float s1 = relu_(fmaf(xvb, wv1[1], bv1[1]));
#pragma unroll
        for (int q = 0; q < 4; q++)
            cb[q] = relu_(fmaf(s0, wv2[q], fmaf(s1, wv2[4 + q], bv2[q])));
        float r0 = relu_(fmaf(xpb, wp1[0], bp1[0]));
        float r1 = relu_(fmaf(xpb, wp1[1], bp1[1]));
#pragma unroll
        for (int q = 0; q < 4; q++)
            cb[4 + q] = relu_(fmaf(r0, wp2[q], fmaf(r1, wp2[4 + q], bp2[q])));
    }

    // ---- pd row i (scalar v_fmac with SGPR weight: 1 instr/MAC) ----
    float pd[16];
#pragma unroll
    for (int k = 0; k < 16; k++) {
        float da = be[k], db = be[k];
#pragma unroll
        for (int f = 0; f < 8; f++) {
            const float wf = we[f * 16 + k];          // uniform -> s_load
            da = fmaf(ca[f], wf, da);
            db = fmaf(cb[f], wf, db);
        }
        pd[k] = relu_(da) + relu_(db);
    }

    // ---- u[i] (regs) and v[i] (LDS) via asm pk_fma with SGPR weights ----
    f32x2 u2[10];
    union { f32x4 q[5]; f32x2 p[10]; } vvu;
#pragma unroll
    for (int c = 0; c < 10; c++) {
        u2[c] = *(const f32x2*)&bc1[2 * c];           // s_load pair -> 2 movs
        vvu.p[c].x = 0.f; vvu.p[c].y = 0.f;
    }
#pragma unroll
    for (int k = 0; k < 16; k++) {
        f32x2 pv; pv.x = pd[k]; pv.y = pd[k];
#pragma unroll
        for (int c = 0; c < 10; c++) {
            pk_fma_sw(u2[c],    pv, *(const f32x2*)&wc1[k * 20 + 2 * c]);
            pk_fma_sw(vvu.p[c], pv, *(const f32x2*)&wc1[(16 + k) * 20 + 2 * c]);
        }
    }
    const int vbase = w * 656 + g * 164 + i * 20;
    if (jh == 0) {
#pragma unroll
        for (int p = 0; p < 5; p++)
            *(f32x4*)&s_v[vbase + 4 * p] = vvu.q[p];  // 5x ds_write_b128
    }
    wave_sync();   // per-wave LDS region; wave lockstep => visible to all lanes

    // ---- stage 4: lane owns (i, jh); FOUR iterations, one j each ----
    const float c0 = ykg[1280];                       // uniform -> s_load
    const int vg = w * 656 + g * 164;
    const float* __restrict__ ykrow = ykg + i * 160;  // + j*20

#pragma unroll 1
    for (int t = 0; t < 4; t++) {
        const int j = jh * 4 + t;

        union { f32x4 q[5]; float f[20]; } va;
#pragma unroll
        for (int p = 0; p < 5; p++)
            va.q[p] = *(const f32x4*)&s_v[vg + j * 20 + 4 * p];  // b128, bcast

        f32x2 sA[10];
#pragma unroll
        for (int c = 0; c < 10; c++)
            sA[c] = *(const f32x2*)&bc2[2 * c];       // SGPR pair -> 2 movs
#pragma unroll
        for (int k = 0; k < 20; k++) {
            const float uk = (k & 1) ? u2[k >> 1].y : u2[k >> 1].x;
            const float hA = relu_(uk + va.f[k]);
            f32x2 hva; hva.x = hA; hva.y = hA;
#pragma unroll
            for (int c = 0; c < 10; c++)
                pk_fma_sw(sA[c], hva, *(const f32x2*)&wc2[k * 20 + 2 * c]);
        }

        // epilogue: z = c0 + sum relu(s2)*yk  (yk row L1-hot, b128 loads)
        union { f32x4 q[5]; f32x2 p[10]; } ya;
#pragma unroll
        for (int p = 0; p < 5; p++)
            ya.q[p] = *(const f32x4*)&ykrow[j * 20 + 4 * p];
        f32x2 z2; z2.x = 0.f; z2.y = 0.f;
#pragma unroll
        for (int c = 0; c < 10; c++)
            pk_fma_vv(z2, pk_relu(sA[c]), ya.p[c]);
        if (b < Btot)
            out[b * 64 + i * 8 + j] = c0 + z2.x + z2.y;
    }
}

extern "C" void kernel_launch(void* const* d_in, const int* in_sizes, int n_in,
                              void* d_out, int out_size, void* d_ws, size_t ws_size,
                              hipStream_t stream) {
    const float* x    = (const float*)d_in[0];
    const float* mask = (const float*)d_in[1];
    const float* wv1  = (const float*)d_in[2];
    const float* bv1  = (const float*)d_in[3];
    const float* wv2  = (const float*)d_in[4];
    const float* bv2  = (const float*)d_in[5];
    const float* wp1  = (const float*)d_in[6];
    const float* bp1  = (const float*)d_in[7];
    const float* wp2  = (const float*)d_in[8];
    const float* bp2  = (const float*)d_in[9];
    const float* we   = (const float*)d_in[10];
    const float* be   = (const float*)d_in[11];
    const float* wc1  = (const float*)d_in[12];
    const float* bc1  = (const float*)d_in[13];
    const float* wc2  = (const float*)d_in[14];
    const float* bc2  = (const float*)d_in[15];
    const float* wm1  = (const float*)d_in[16];
    const float* bm1  = (const float*)d_in[17];
    const float* wm2  = (const float*)d_in[18];
    const float* bm2  = (const float*)d_in[19];
    const float* wm3  = (const float*)d_in[20];
    const float* bm3  = (const float*)d_in[21];
    const float* wk1  = (const float*)d_in[22];
    const float* bk1  = (const float*)d_in[23];
    const float* wk2  = (const float*)d_in[24];
    const float* bk2  = (const float*)d_in[25];
    float* out = (float*)d_out;
    float* ws  = (float*)d_ws;

    int Btot = in_sizes[0] / 16;                 // 32768

    yk_kernel<<<1, 256, 0, stream>>>(mask, wm1, bm1, wm2, bm2, wm3, bm3,
                                     wk1, bk1, wk2, bk2, ws);

    int grid = (Btot + 15) / 16;                 // 16 batches per 256-thr block
    frap_kernel<<<grid, 256, 0, stream>>>(
        x, wv1, bv1, wv2, bv2, wp1, bp1, wp2, bp2, we, be,
        wc1, bc1, wc2, bc2, ws, out, Btot);
}